// Round 5
// baseline (385.261 us; speedup 1.0000x reference)
//
#include <hip/hip_runtime.h>
#include <math.h>

#define T_DIM 64
#define C_DIM 256
#define H_DIM 56
#define W_DIM 56
#define HW    (H_DIM * W_DIM)        // 3136
#define HW4   (HW / 4)               // 784
#define CHW   (C_DIM * HW)
#define THW   (T_DIM * HW)           // 200704

// ---------------------------------------------------------------------------
// Gate kernel: register-blocked conv, no LDS, no shfl.
// blockIdx.x = (side*S + g) * 32 + tq   -> side/g BLOCK-UNIFORM (s_load weights)
// wave: hh = waveid&1, t = tq*2 + (waveid>>1)
// lane: wg = lane&15 (active<14), rg = lane>>4; rows r0..r0+6, cols w0..w0+3.
// Per (ch,dt): preload 9 rows x 6 floats (f4 + 2 edge scalars), then 252 FMAs
// with SGPR weights. Writes partial plane pbuf[side*S+g].
// ---------------------------------------------------------------------------
template<int S>
__global__ __launch_bounds__(256, 4) void gate_kernel(
    const float* __restrict__ x,
    const float* __restrict__ w_l,
    const float* __restrict__ w_r,
    float* __restrict__ pbuf)
{
    constexpr int CPG = 64 / S;

    const int bx   = blockIdx.x;
    const int tq   = bx & 31;
    const int sg   = bx >> 5;            // side*S + g   (block-uniform)
    const int side = sg / S;
    const int g    = sg & (S - 1);

    const int waveid = __builtin_amdgcn_readfirstlane((int)(threadIdx.x >> 6));
    const int hh = waveid & 1;
    const int t  = tq * 2 + (waveid >> 1);

    const int lane = threadIdx.x & 63;
    const int wg   = lane & 15;
    const int rg   = lane >> 4;
    const bool act = (wg < 14);
    const int w0   = act ? wg * 4 : 52;
    const int r0   = hh * 28 + rg * 7;
    const bool have_l = (wg > 0);
    const bool have_r = (wg < 13);
    const int  off0   = have_l ? -1 : 0;
    const int  off5   = have_r ?  4 : 0;

    const float* wtab = (side ? w_r : w_l) + g * CPG * 27;   // uniform
    const int c0 = side * 64 + g * CPG;

    const int tm = (t + 63) & 63, tp = (t + 1) & 63;
    const float* tbase[3] = { x + (size_t)tm * CHW,
                              x + (size_t)t  * CHW,
                              x + (size_t)tp * CHW };

    float acc[7][4];
    #pragma unroll
    for (int j = 0; j < 7; ++j)
        #pragma unroll
        for (int k = 0; k < 4; ++k) acc[j][k] = 0.f;

    for (int ci = 0; ci < CPG; ++ci) {
        float wgt[27];
        #pragma unroll
        for (int k = 0; k < 27; ++k) wgt[k] = wtab[ci * 27 + k];   // s_load

        #pragma unroll
        for (int dt = 0; dt < 3; ++dt) {
            const float* plane = tbase[dt] + (size_t)(c0 + ci) * HW;

            // ---- preload 9 source rows (w0-1 .. w0+4) ----
            float f[9][6];
            #pragma unroll
            for (int s9 = 0; s9 < 9; ++s9) {
                const int sr = r0 - 1 + s9;
                bool rv = true;
                int  srow = sr;
                if (s9 == 0)      { rv = (sr >= 0);     srow = rv ? sr : 0; }
                else if (s9 == 8) { rv = (sr < H_DIM);  srow = rv ? sr : (H_DIM - 1); }

                const float* row = plane + srow * W_DIM;
                float4 m  = *(const float4*)(row + w0);
                float  e0 = row[w0 + off0];
                float  e5 = row[w0 + off5];

                f[s9][0] = have_l ? e0 : 0.f;
                f[s9][1] = m.x; f[s9][2] = m.y; f[s9][3] = m.z; f[s9][4] = m.w;
                f[s9][5] = have_r ? e5 : 0.f;
                if ((s9 == 0 || s9 == 8) && !rv) {
                    f[s9][0] = 0.f; f[s9][1] = 0.f; f[s9][2] = 0.f;
                    f[s9][3] = 0.f; f[s9][4] = 0.f; f[s9][5] = 0.f;
                }
            }

            // ---- 252 FMAs, weights from SGPRs ----
            #pragma unroll
            for (int s9 = 0; s9 < 9; ++s9) {
                const int jlo = (s9 >= 2) ? s9 - 2 : 0;
                const int jhi = (s9 <= 6) ? s9 : 6;
                #pragma unroll
                for (int j = jlo; j <= jhi; ++j) {
                    const int dh = s9 - j;
                    const float w0t = wgt[dt * 9 + dh * 3 + 0];
                    const float w1t = wgt[dt * 9 + dh * 3 + 1];
                    const float w2t = wgt[dt * 9 + dh * 3 + 2];
                    #pragma unroll
                    for (int k = 0; k < 4; ++k)
                        acc[j][k] += w0t * f[s9][k] + w1t * f[s9][k + 1] + w2t * f[s9][k + 2];
                }
            }
        }
    }

    if (act) {
        float* pp = pbuf + (size_t)sg * THW
                         + (size_t)t * HW + r0 * W_DIM + w0;
        #pragma unroll
        for (int j = 0; j < 7; ++j) {
            float4 v; v.x = acc[j][0]; v.y = acc[j][1]; v.z = acc[j][2]; v.w = acc[j][3];
            *(float4*)(pp + j * W_DIM) = v;
        }
    }
}

// ---------------------------------------------------------------------------
// Reduce S partials per side + bias + tanh -> gbuf (gl at 0, gr at THW).
// ---------------------------------------------------------------------------
template<int S>
__global__ __launch_bounds__(256) void reduce_tanh_kernel(
    const float* __restrict__ pbuf,
    float* __restrict__ gbuf,
    const float* __restrict__ b_l,
    const float* __restrict__ b_r)
{
    const int i = blockIdx.x * 256 + threadIdx.x;   // over THW/4
    const float4* p4 = (const float4*)pbuf;
    float4* g4 = (float4*)gbuf;

    float4 a = {0.f,0.f,0.f,0.f}, b = {0.f,0.f,0.f,0.f};
    #pragma unroll
    for (int g = 0; g < S; ++g) {
        float4 va = p4[(size_t)g       * (THW/4) + i];
        float4 vb = p4[(size_t)(S + g) * (THW/4) + i];
        a.x += va.x; a.y += va.y; a.z += va.z; a.w += va.w;
        b.x += vb.x; b.y += vb.y; b.z += vb.z; b.w += vb.w;
    }
    const float bl = b_l[0], br = b_r[0];
    float4 gl, gr;
    gl.x = tanhf(a.x + bl); gl.y = tanhf(a.y + bl);
    gl.z = tanhf(a.z + bl); gl.w = tanhf(a.w + bl);
    gr.x = tanhf(b.x + br); gr.y = tanhf(b.y + br);
    gr.z = tanhf(b.z + br); gr.w = tanhf(b.w + br);
    g4[i]           = gl;
    g4[(THW/4) + i] = gr;
}

// ---------------------------------------------------------------------------
// Combine: thread owns (c,h,w4), iterates 16 t's carrying x/g in registers.
// ---------------------------------------------------------------------------
__global__ __launch_bounds__(256) void combine_kernel(
    const float* __restrict__ x,
    const float* __restrict__ g,
    float* __restrict__ out)
{
    const int tid = blockIdx.x * 256 + threadIdx.x;   // (c*784 + h*14 + w4)
    const int t0  = blockIdx.y * 16;
    const int c   = tid / HW4;
    const int gb  = tid - c * HW4;

    const float4* x4 = (const float4*)x;
    float4*       o4 = (float4*)out;
    const size_t  ts = C_DIM * HW4;
    const size_t  base = tid;

    if (c >= 128) {
        #pragma unroll 4
        for (int i = 0; i < 16; ++i) {
            const size_t idx = (size_t)(t0 + i) * ts + base;
            o4[idx] = x4[idx];
        }
    } else if (c < 64) {
        const float4* gl4 = (const float4*)g;
        float4 xv = x4[(size_t)t0 * ts + base];
        float4 g0 = gl4[t0 * HW4 + gb];
        #pragma unroll 4
        for (int i = 0; i < 16; ++i) {
            const int t  = t0 + i;
            const int tp = (t + 1) & 63;
            float4 xn = x4[(size_t)tp * ts + base];
            float4 g1 = gl4[tp * HW4 + gb];
            float4 r;
            r.x = xv.x - g0.x * xv.x + g1.x * xn.x;
            r.y = xv.y - g0.y * xv.y + g1.y * xn.y;
            r.z = xv.z - g0.z * xv.z + g1.z * xn.z;
            r.w = xv.w - g0.w * xv.w + g1.w * xn.w;
            o4[(size_t)t * ts + base] = r;
            xv = xn; g0 = g1;
        }
    } else {
        const float4* gr4 = (const float4*)(g + THW);
        const int tmi = (t0 + 63) & 63;
        float4 xm = x4[(size_t)tmi * ts + base];
        float4 gm = gr4[tmi * HW4 + gb];
        #pragma unroll 4
        for (int i = 0; i < 16; ++i) {
            const int t = t0 + i;
            float4 xv = x4[(size_t)t * ts + base];
            float4 g0 = gr4[t * HW4 + gb];
            float4 r;
            r.x = xv.x - g0.x * xv.x + gm.x * xm.x;
            r.y = xv.y - g0.y * xv.y + gm.y * xm.y;
            r.z = xv.z - g0.z * xv.z + gm.z * xm.z;
            r.w = xv.w - g0.w * xv.w + gm.w * xm.w;
            o4[(size_t)t * ts + base] = r;
            xm = xv; gm = g0;
        }
    }
}

template<int S>
static void launch_all(const float* x, const float* w_l, const float* b_l,
                       const float* w_r, const float* b_r,
                       float* out, float* ws, hipStream_t stream)
{
    float* pbuf = ws;                          // 2*S partial planes
    float* gbuf = ws + (size_t)(2 * S) * THW;  // 2 gate planes
    gate_kernel<S><<<2 * S * 32, 256, 0, stream>>>(x, w_l, w_r, pbuf);
    reduce_tanh_kernel<S><<<THW / 4 / 256, 256, 0, stream>>>(pbuf, gbuf, b_l, b_r);
    combine_kernel<<<dim3(HW4 * C_DIM / 256, 4), 256, 0, stream>>>(x, gbuf, out);
}

extern "C" void kernel_launch(void* const* d_in, const int* in_sizes, int n_in,
                              void* d_out, int out_size, void* d_ws, size_t ws_size,
                              hipStream_t stream) {
    const float* x   = (const float*)d_in[0];
    const float* w_l = (const float*)d_in[1];
    const float* b_l = (const float*)d_in[2];
    const float* w_r = (const float*)d_in[3];
    const float* b_r = (const float*)d_in[4];
    float* out = (float*)d_out;
    float* ws  = (float*)d_ws;

    const size_t plane_bytes = (size_t)THW * 4;
    if (ws_size >= 34 * plane_bytes)
        launch_all<16>(x, w_l, b_l, w_r, b_r, out, ws, stream);
    else if (ws_size >= 18 * plane_bytes)
        launch_all<8>(x, w_l, b_l, w_r, b_r, out, ws, stream);
    else
        launch_all<4>(x, w_l, b_l, w_r, b_r, out, ws, stream);
}

// Round 6
// 366.877 us; speedup vs baseline: 1.0501x; 1.0501x over previous
//
#include <hip/hip_runtime.h>
#include <math.h>

#define T_DIM 64
#define C_DIM 256
#define H_DIM 56
#define W_DIM 56
#define HW    (H_DIM * W_DIM)        // 3136
#define HW4   (HW / 4)               // 784
#define CHW   (C_DIM * HW)
#define THW   (T_DIM * HW)           // 200704

// ---------------------------------------------------------------------------
// Gate kernel: register-blocked conv, no LDS, no shfl, no spills.
// blockIdx.x = sg*32 + tq, sg = side*S+g  (BLOCK-UNIFORM -> weights in SGPRs)
// wave: hh = waveid&1, t = tq*2 + (waveid>>1)
// lane: wg = lane&15 (active<14), rg = lane>>4; rows r0..r0+6, cols w0..w0+3.
// Per (ci,dt): row-at-a-time load (float4 + 2 edge scalars) -> immediate FMAs.
// Live VGPR state: 6 f + 28 acc + addressing  (~60).
// ---------------------------------------------------------------------------
template<int S>
__global__ __launch_bounds__(256, 4) void gate_kernel(
    const float* __restrict__ x,
    const float* __restrict__ w_l,
    const float* __restrict__ w_r,
    float* __restrict__ pbuf)
{
    constexpr int CPG = 64 / S;

    const int bx   = blockIdx.x;
    const int tq   = bx & 31;
    const int sg   = bx >> 5;            // block-uniform
    const int side = sg / S;
    const int g    = sg & (S - 1);

    const int waveid = __builtin_amdgcn_readfirstlane((int)(threadIdx.x >> 6));
    const int hh = waveid & 1;
    const int t  = tq * 2 + (waveid >> 1);

    const int lane = threadIdx.x & 63;
    const int wg   = lane & 15;
    const int rg   = lane >> 4;
    const bool act = (wg < 14);
    const int w0   = act ? wg * 4 : 52;
    const int r0   = hh * 28 + rg * 7;
    const bool have_l = (wg > 0);
    const bool have_r = (wg < 13);
    const int  off0   = have_l ? -1 : 0;
    const int  off5   = have_r ?  4 : 0;

    const float* wtab = (side ? w_r : w_l) + g * CPG * 27;   // uniform
    const int c0 = side * 64 + g * CPG;

    const int tm = (t + 63) & 63, tp = (t + 1) & 63;
    const float* tbase[3] = { x + (size_t)tm * CHW,
                              x + (size_t)t  * CHW,
                              x + (size_t)tp * CHW };

    float acc[7][4];
    #pragma unroll
    for (int j = 0; j < 7; ++j)
        #pragma unroll
        for (int k = 0; k < 4; ++k) acc[j][k] = 0.f;

    for (int ci = 0; ci < CPG; ++ci) {
        float wgt[27];
        #pragma unroll
        for (int k = 0; k < 27; ++k) wgt[k] = wtab[ci * 27 + k];   // s_load

        #pragma unroll
        for (int dt = 0; dt < 3; ++dt) {
            const float* plane = tbase[dt] + (size_t)(c0 + ci) * HW;

            #pragma unroll
            for (int s9 = 0; s9 < 9; ++s9) {
                const int sr = r0 - 1 + s9;
                bool rv = true;
                int  srow = sr;
                if (s9 == 0)      { rv = (sr >= 0);     srow = rv ? sr : 0; }
                else if (s9 == 8) { rv = (sr < H_DIM);  srow = rv ? sr : (H_DIM - 1); }

                const float* row = plane + srow * W_DIM;
                float4 m  = *(const float4*)(row + w0);
                float  e0 = row[w0 + off0];
                float  e5 = row[w0 + off5];

                float f0 = have_l ? e0 : 0.f;
                float f1 = m.x, f2 = m.y, f3 = m.z, f4v = m.w;
                float f5 = have_r ? e5 : 0.f;
                if ((s9 == 0 || s9 == 8) && !rv) {
                    f0 = 0.f; f1 = 0.f; f2 = 0.f; f3 = 0.f; f4v = 0.f; f5 = 0.f;
                }
                float f[6] = { f0, f1, f2, f3, f4v, f5 };

                const int jlo = (s9 >= 2) ? s9 - 2 : 0;
                const int jhi = (s9 <= 6) ? s9 : 6;
                #pragma unroll
                for (int j = jlo; j <= jhi; ++j) {
                    const int dh = s9 - j;
                    const float w0t = wgt[dt * 9 + dh * 3 + 0];
                    const float w1t = wgt[dt * 9 + dh * 3 + 1];
                    const float w2t = wgt[dt * 9 + dh * 3 + 2];
                    #pragma unroll
                    for (int k = 0; k < 4; ++k)
                        acc[j][k] += w0t * f[k] + w1t * f[k + 1] + w2t * f[k + 2];
                }
            }
        }
    }

    if (act) {
        float* pp = pbuf + (size_t)sg * THW
                         + (size_t)t * HW + r0 * W_DIM + w0;
        #pragma unroll
        for (int j = 0; j < 7; ++j) {
            float4 v; v.x = acc[j][0]; v.y = acc[j][1]; v.z = acc[j][2]; v.w = acc[j][3];
            *(float4*)(pp + j * W_DIM) = v;
        }
    }
}

// ---------------------------------------------------------------------------
// Reduce S partials per side + bias + tanh -> gbuf (gl at 0, gr at THW).
// ---------------------------------------------------------------------------
template<int S>
__global__ __launch_bounds__(256) void reduce_tanh_kernel(
    const float* __restrict__ pbuf,
    float* __restrict__ gbuf,
    const float* __restrict__ b_l,
    const float* __restrict__ b_r)
{
    const int i = blockIdx.x * 256 + threadIdx.x;   // over THW/4
    const float4* p4 = (const float4*)pbuf;
    float4* g4 = (float4*)gbuf;

    float4 a = {0.f,0.f,0.f,0.f}, b = {0.f,0.f,0.f,0.f};
    #pragma unroll
    for (int g = 0; g < S; ++g) {
        float4 va = p4[(size_t)g       * (THW/4) + i];
        float4 vb = p4[(size_t)(S + g) * (THW/4) + i];
        a.x += va.x; a.y += va.y; a.z += va.z; a.w += va.w;
        b.x += vb.x; b.y += vb.y; b.z += vb.z; b.w += vb.w;
    }
    const float bl = b_l[0], br = b_r[0];
    float4 gl, gr;
    gl.x = tanhf(a.x + bl); gl.y = tanhf(a.y + bl);
    gl.z = tanhf(a.z + bl); gl.w = tanhf(a.w + bl);
    gr.x = tanhf(b.x + br); gr.y = tanhf(b.y + br);
    gr.z = tanhf(b.z + br); gr.w = tanhf(b.w + br);
    g4[i]           = gl;
    g4[(THW/4) + i] = gr;
}

// ---------------------------------------------------------------------------
// Combine: thread owns (c,h,w4), iterates 16 t's carrying x/g in registers.
// ---------------------------------------------------------------------------
__global__ __launch_bounds__(256) void combine_kernel(
    const float* __restrict__ x,
    const float* __restrict__ g,
    float* __restrict__ out)
{
    const int tid = blockIdx.x * 256 + threadIdx.x;   // (c*784 + h*14 + w4)
    const int t0  = blockIdx.y * 16;
    const int c   = tid / HW4;
    const int gb  = tid - c * HW4;

    const float4* x4 = (const float4*)x;
    float4*       o4 = (float4*)out;
    const size_t  ts = C_DIM * HW4;
    const size_t  base = tid;

    if (c >= 128) {
        #pragma unroll 4
        for (int i = 0; i < 16; ++i) {
            const size_t idx = (size_t)(t0 + i) * ts + base;
            o4[idx] = x4[idx];
        }
    } else if (c < 64) {
        const float4* gl4 = (const float4*)g;
        float4 xv = x4[(size_t)t0 * ts + base];
        float4 g0 = gl4[t0 * HW4 + gb];
        #pragma unroll 4
        for (int i = 0; i < 16; ++i) {
            const int t  = t0 + i;
            const int tp = (t + 1) & 63;
            float4 xn = x4[(size_t)tp * ts + base];
            float4 g1 = gl4[tp * HW4 + gb];
            float4 r;
            r.x = xv.x - g0.x * xv.x + g1.x * xn.x;
            r.y = xv.y - g0.y * xv.y + g1.y * xn.y;
            r.z = xv.z - g0.z * xv.z + g1.z * xn.z;
            r.w = xv.w - g0.w * xv.w + g1.w * xn.w;
            o4[(size_t)t * ts + base] = r;
            xv = xn; g0 = g1;
        }
    } else {
        const float4* gr4 = (const float4*)(g + THW);
        const int tmi = (t0 + 63) & 63;
        float4 xm = x4[(size_t)tmi * ts + base];
        float4 gm = gr4[tmi * HW4 + gb];
        #pragma unroll 4
        for (int i = 0; i < 16; ++i) {
            const int t = t0 + i;
            float4 xv = x4[(size_t)t * ts + base];
            float4 g0 = gr4[t * HW4 + gb];
            float4 r;
            r.x = xv.x - g0.x * xv.x + gm.x * xm.x;
            r.y = xv.y - g0.y * xv.y + gm.y * xm.y;
            r.z = xv.z - g0.z * xv.z + gm.z * xm.z;
            r.w = xv.w - g0.w * xv.w + gm.w * xm.w;
            o4[(size_t)t * ts + base] = r;
            xm = xv; gm = g0;
        }
    }
}

template<int S>
static void launch_all(const float* x, const float* w_l, const float* b_l,
                       const float* w_r, const float* b_r,
                       float* out, float* ws, hipStream_t stream)
{
    float* pbuf = ws;                          // 2*S partial planes
    float* gbuf = ws + (size_t)(2 * S) * THW;  // 2 gate planes
    gate_kernel<S><<<2 * S * 32, 256, 0, stream>>>(x, w_l, w_r, pbuf);
    reduce_tanh_kernel<S><<<THW / 4 / 256, 256, 0, stream>>>(pbuf, gbuf, b_l, b_r);
    combine_kernel<<<dim3(HW4 * C_DIM / 256, 4), 256, 0, stream>>>(x, gbuf, out);
}

extern "C" void kernel_launch(void* const* d_in, const int* in_sizes, int n_in,
                              void* d_out, int out_size, void* d_ws, size_t ws_size,
                              hipStream_t stream) {
    const float* x   = (const float*)d_in[0];
    const float* w_l = (const float*)d_in[1];
    const float* b_l = (const float*)d_in[2];
    const float* w_r = (const float*)d_in[3];
    const float* b_r = (const float*)d_in[4];
    float* out = (float*)d_out;
    float* ws  = (float*)d_ws;

    const size_t plane_bytes = (size_t)THW * 4;
    if (ws_size >= 34 * plane_bytes)
        launch_all<16>(x, w_l, b_l, w_r, b_r, out, ws, stream);
    else if (ws_size >= 18 * plane_bytes)
        launch_all<8>(x, w_l, b_l, w_r, b_r, out, ws, stream);
    else
        launch_all<4>(x, w_l, b_l, w_r, b_r, out, ws, stream);
}

// Round 7
// 165.993 us; speedup vs baseline: 2.3210x; 2.2102x over previous
//
#include <hip/hip_runtime.h>
#include <math.h>

#define T_DIM 64
#define C_DIM 256
#define H_DIM 56
#define W_DIM 56
#define HW    (H_DIM * W_DIM)        // 3136
#define HW4   (HW / 4)               // 784
#define CHW   (C_DIM * HW)
#define THW   (T_DIM * HW)           // 200704

// force a (block-uniform) float into an SGPR
__device__ __forceinline__ float rfl(float v) {
    return __int_as_float(__builtin_amdgcn_readfirstlane(__float_as_int(v)));
}

// ---------------------------------------------------------------------------
// Gate kernel: register-blocked conv, no LDS, no spills.
// blockIdx.x = sg*32 + tq, sg = side*S+g  (block-uniform -> weights to SGPRs
// via readfirstlane). wave: hh = waveid&1, t = tq*2 + (waveid>>1).
// lane: wg = lane&15 (active<14), rg = lane>>4; rows r0..r0+6, cols w0..w0+3.
// Per (ci,dt): row-at-a-time load (float4 + 2 edge scalars) -> immediate FMAs.
// Live VGPR state: ~6 row + 28 acc + addressing (~60); weights in SGPRs.
// ---------------------------------------------------------------------------
template<int S>
__global__ __launch_bounds__(256) void gate_kernel(
    const float* __restrict__ x,
    const float* __restrict__ w_l,
    const float* __restrict__ w_r,
    float* __restrict__ pbuf)
{
    constexpr int CPG = 64 / S;

    const int bx   = blockIdx.x;
    const int tq   = bx & 31;
    const int sg   = bx >> 5;            // block-uniform
    const int side = sg / S;
    const int g    = sg & (S - 1);

    const int waveid = __builtin_amdgcn_readfirstlane((int)(threadIdx.x >> 6));
    const int hh = waveid & 1;
    const int t  = tq * 2 + (waveid >> 1);

    const int lane = threadIdx.x & 63;
    const int wg   = lane & 15;
    const int rg   = lane >> 4;
    const bool act = (wg < 14);
    const int w0   = act ? wg * 4 : 52;
    const int r0   = hh * 28 + rg * 7;
    const bool have_l = (wg > 0);
    const bool have_r = (wg < 13);
    const int  off0   = have_l ? -1 : 0;
    const int  off5   = have_r ?  4 : 0;

    const float* wtab = (side ? w_r : w_l) + g * CPG * 27;   // uniform
    const int c0 = side * 64 + g * CPG;

    const int tm = (t + 63) & 63, tp = (t + 1) & 63;
    const float* tbase[3] = { x + (size_t)tm * CHW,
                              x + (size_t)t  * CHW,
                              x + (size_t)tp * CHW };

    float acc[7][4];
    #pragma unroll
    for (int j = 0; j < 7; ++j)
        #pragma unroll
        for (int k = 0; k < 4; ++k) acc[j][k] = 0.f;

    #pragma unroll 1
    for (int ci = 0; ci < CPG; ++ci) {
        float wgt[27];
        #pragma unroll
        for (int k = 0; k < 27; ++k) wgt[k] = rfl(wtab[ci * 27 + k]);  // SGPRs

        #pragma unroll
        for (int dt = 0; dt < 3; ++dt) {
            const float* plane = tbase[dt] + (size_t)(c0 + ci) * HW;

            #pragma unroll
            for (int s9 = 0; s9 < 9; ++s9) {
                const int sr = r0 - 1 + s9;
                bool rv = true;
                int  srow = sr;
                if (s9 == 0)      { rv = (sr >= 0);     srow = rv ? sr : 0; }
                else if (s9 == 8) { rv = (sr < H_DIM);  srow = rv ? sr : (H_DIM - 1); }

                const float* row = plane + srow * W_DIM;
                float4 m  = *(const float4*)(row + w0);
                float  e0 = row[w0 + off0];
                float  e5 = row[w0 + off5];

                float f0 = have_l ? e0 : 0.f;
                float f1 = m.x, f2 = m.y, f3 = m.z, f4v = m.w;
                float f5 = have_r ? e5 : 0.f;
                if ((s9 == 0 || s9 == 8) && !rv) {
                    f0 = 0.f; f1 = 0.f; f2 = 0.f; f3 = 0.f; f4v = 0.f; f5 = 0.f;
                }
                float f[6] = { f0, f1, f2, f3, f4v, f5 };

                const int jlo = (s9 >= 2) ? s9 - 2 : 0;
                const int jhi = (s9 <= 6) ? s9 : 6;
                #pragma unroll
                for (int j = jlo; j <= jhi; ++j) {
                    const int dh = s9 - j;
                    const float w0t = wgt[dt * 9 + dh * 3 + 0];
                    const float w1t = wgt[dt * 9 + dh * 3 + 1];
                    const float w2t = wgt[dt * 9 + dh * 3 + 2];
                    #pragma unroll
                    for (int k = 0; k < 4; ++k)
                        acc[j][k] += w0t * f[k] + w1t * f[k + 1] + w2t * f[k + 2];
                }
            }
        }
    }

    if (act) {
        float* pp = pbuf + (size_t)sg * THW
                         + (size_t)t * HW + r0 * W_DIM + w0;
        #pragma unroll
        for (int j = 0; j < 7; ++j) {
            float4 v; v.x = acc[j][0]; v.y = acc[j][1]; v.z = acc[j][2]; v.w = acc[j][3];
            *(float4*)(pp + j * W_DIM) = v;
        }
    }
}

// ---------------------------------------------------------------------------
// Reduce S partials per side + bias + tanh -> gbuf (gl at 0, gr at THW).
// ---------------------------------------------------------------------------
template<int S>
__global__ __launch_bounds__(256) void reduce_tanh_kernel(
    const float* __restrict__ pbuf,
    float* __restrict__ gbuf,
    const float* __restrict__ b_l,
    const float* __restrict__ b_r)
{
    const int i = blockIdx.x * 256 + threadIdx.x;   // over THW/4
    const float4* p4 = (const float4*)pbuf;
    float4* g4 = (float4*)gbuf;

    float4 a = {0.f,0.f,0.f,0.f}, b = {0.f,0.f,0.f,0.f};
    #pragma unroll
    for (int g = 0; g < S; ++g) {
        float4 va = p4[(size_t)g       * (THW/4) + i];
        float4 vb = p4[(size_t)(S + g) * (THW/4) + i];
        a.x += va.x; a.y += va.y; a.z += va.z; a.w += va.w;
        b.x += vb.x; b.y += vb.y; b.z += vb.z; b.w += vb.w;
    }
    const float bl = b_l[0], br = b_r[0];
    float4 gl, gr;
    gl.x = tanhf(a.x + bl); gl.y = tanhf(a.y + bl);
    gl.z = tanhf(a.z + bl); gl.w = tanhf(a.w + bl);
    gr.x = tanhf(b.x + br); gr.y = tanhf(b.y + br);
    gr.z = tanhf(b.z + br); gr.w = tanhf(b.w + br);
    g4[i]           = gl;
    g4[(THW/4) + i] = gr;
}

// ---------------------------------------------------------------------------
// Combine: thread owns (c,h,w4), iterates 16 t's carrying x/g in registers.
// ---------------------------------------------------------------------------
__global__ __launch_bounds__(256) void combine_kernel(
    const float* __restrict__ x,
    const float* __restrict__ g,
    float* __restrict__ out)
{
    const int tid = blockIdx.x * 256 + threadIdx.x;   // (c*784 + h*14 + w4)
    const int t0  = blockIdx.y * 16;
    const int c   = tid / HW4;
    const int gb  = tid - c * HW4;

    const float4* x4 = (const float4*)x;
    float4*       o4 = (float4*)out;
    const size_t  ts = C_DIM * HW4;
    const size_t  base = tid;

    if (c >= 128) {
        #pragma unroll 4
        for (int i = 0; i < 16; ++i) {
            const size_t idx = (size_t)(t0 + i) * ts + base;
            o4[idx] = x4[idx];
        }
    } else if (c < 64) {
        const float4* gl4 = (const float4*)g;
        float4 xv = x4[(size_t)t0 * ts + base];
        float4 g0 = gl4[t0 * HW4 + gb];
        #pragma unroll 4
        for (int i = 0; i < 16; ++i) {
            const int t  = t0 + i;
            const int tp = (t + 1) & 63;
            float4 xn = x4[(size_t)tp * ts + base];
            float4 g1 = gl4[tp * HW4 + gb];
            float4 r;
            r.x = xv.x - g0.x * xv.x + g1.x * xn.x;
            r.y = xv.y - g0.y * xv.y + g1.y * xn.y;
            r.z = xv.z - g0.z * xv.z + g1.z * xn.z;
            r.w = xv.w - g0.w * xv.w + g1.w * xn.w;
            o4[(size_t)t * ts + base] = r;
            xv = xn; g0 = g1;
        }
    } else {
        const float4* gr4 = (const float4*)(g + THW);
        const int tmi = (t0 + 63) & 63;
        float4 xm = x4[(size_t)tmi * ts + base];
        float4 gm = gr4[tmi * HW4 + gb];
        #pragma unroll 4
        for (int i = 0; i < 16; ++i) {
            const int t = t0 + i;
            float4 xv = x4[(size_t)t * ts + base];
            float4 g0 = gr4[t * HW4 + gb];
            float4 r;
            r.x = xv.x - g0.x * xv.x + gm.x * xm.x;
            r.y = xv.y - g0.y * xv.y + gm.y * xm.y;
            r.z = xv.z - g0.z * xv.z + gm.z * xm.z;
            r.w = xv.w - g0.w * xv.w + gm.w * xm.w;
            o4[(size_t)t * ts + base] = r;
            xm = xv; gm = g0;
        }
    }
}

template<int S>
static void launch_all(const float* x, const float* w_l, const float* b_l,
                       const float* w_r, const float* b_r,
                       float* out, float* ws, hipStream_t stream)
{
    float* pbuf = ws;                          // 2*S partial planes
    float* gbuf = ws + (size_t)(2 * S) * THW;  // 2 gate planes
    gate_kernel<S><<<2 * S * 32, 256, 0, stream>>>(x, w_l, w_r, pbuf);
    reduce_tanh_kernel<S><<<THW / 4 / 256, 256, 0, stream>>>(pbuf, gbuf, b_l, b_r);
    combine_kernel<<<dim3(HW4 * C_DIM / 256, 4), 256, 0, stream>>>(x, gbuf, out);
}

extern "C" void kernel_launch(void* const* d_in, const int* in_sizes, int n_in,
                              void* d_out, int out_size, void* d_ws, size_t ws_size,
                              hipStream_t stream) {
    const float* x   = (const float*)d_in[0];
    const float* w_l = (const float*)d_in[1];
    const float* b_l = (const float*)d_in[2];
    const float* w_r = (const float*)d_in[3];
    const float* b_r = (const float*)d_in[4];
    float* out = (float*)d_out;
    float* ws  = (float*)d_ws;

    const size_t plane_bytes = (size_t)THW * 4;
    if (ws_size >= 34 * plane_bytes)
        launch_all<16>(x, w_l, b_l, w_r, b_r, out, ws, stream);
    else if (ws_size >= 18 * plane_bytes)
        launch_all<8>(x, w_l, b_l, w_r, b_r, out, ws, stream);
    else
        launch_all<4>(x, w_l, b_l, w_r, b_r, out, ws, stream);
}

// Round 9
// 113.392 us; speedup vs baseline: 3.3976x; 1.4639x over previous
//
#include <hip/hip_runtime.h>
#include <math.h>

#define T_DIM 64
#define C_DIM 256
#define H_DIM 56
#define W_DIM 56
#define HW    (H_DIM * W_DIM)        // 3136
#define HW4   (HW / 4)               // 784
#define CHW   (C_DIM * HW)
#define THW   (T_DIM * HW)           // 200704

typedef float nt_float4 __attribute__((ext_vector_type(4)));

// force a (block-uniform) float into an SGPR
__device__ __forceinline__ float rfl(float v) {
    return __int_as_float(__builtin_amdgcn_readfirstlane(__float_as_int(v)));
}

// ---------------------------------------------------------------------------
// Gate kernel: register-blocked conv, no LDS, no spills, shfl-halo.
// blockIdx.x = sg*32 + tq, sg = side*S+g (block-uniform -> weights to SGPRs).
// wave: hh = waveid&1, t = tq*2 + (waveid>>1).
// lane: wg = lane&15 (active<14), rg = lane>>4; rows r0..r0+6, cols w0..w0+3.
// Per (ci,dt,row): ONE float4 load; halo cols from neighbor lanes via shfl.
// ---------------------------------------------------------------------------
template<int S>
__global__ __launch_bounds__(256) void gate_kernel(
    const float* __restrict__ x,
    const float* __restrict__ w_l,
    const float* __restrict__ w_r,
    float* __restrict__ pbuf)
{
    constexpr int CPG = 64 / S;

    const int bx   = blockIdx.x;
    const int tq   = bx & 31;
    const int sg   = bx >> 5;            // block-uniform
    const int side = sg / S;
    const int g    = sg & (S - 1);

    const int waveid = __builtin_amdgcn_readfirstlane((int)(threadIdx.x >> 6));
    const int hh = waveid & 1;
    const int t  = tq * 2 + (waveid >> 1);

    const int lane = threadIdx.x & 63;
    const int wg   = lane & 15;
    const int rg   = lane >> 4;
    const bool act = (wg < 14);
    const int w0   = act ? wg * 4 : 52;
    const int r0   = hh * 28 + rg * 7;
    const bool have_l = (wg > 0);
    const bool have_r = (wg < 13);

    const float* wtab = (side ? w_r : w_l) + g * CPG * 27;   // uniform
    const int c0 = side * 64 + g * CPG;

    const int tm = (t + 63) & 63, tp = (t + 1) & 63;
    const float* tbase[3] = { x + (size_t)tm * CHW,
                              x + (size_t)t  * CHW,
                              x + (size_t)tp * CHW };

    float acc[7][4];
    #pragma unroll
    for (int j = 0; j < 7; ++j)
        #pragma unroll
        for (int k = 0; k < 4; ++k) acc[j][k] = 0.f;

    #pragma unroll 1
    for (int ci = 0; ci < CPG; ++ci) {
        float wgt[27];
        #pragma unroll
        for (int k = 0; k < 27; ++k) wgt[k] = rfl(wtab[ci * 27 + k]);  // SGPRs

        #pragma unroll
        for (int dt = 0; dt < 3; ++dt) {
            const float* plane = tbase[dt] + (size_t)(c0 + ci) * HW;

            #pragma unroll
            for (int s9 = 0; s9 < 9; ++s9) {
                const int sr = r0 - 1 + s9;
                bool rv = true;
                int  srow = sr;
                if (s9 == 0)      { rv = (sr >= 0);     srow = rv ? sr : 0; }
                else if (s9 == 8) { rv = (sr < H_DIM);  srow = rv ? sr : (H_DIM - 1); }

                const float* row = plane + srow * W_DIM;
                float4 m  = *(const float4*)(row + w0);
                float  fl = __shfl_up(m.w, 1);    // lane-1's row[w0+3] == row[w0-1]
                float  fr = __shfl_down(m.x, 1);  // lane+1's row[w0]   == row[w0+4]

                float f0 = have_l ? fl : 0.f;
                float f1 = m.x, f2 = m.y, f3 = m.z, f4v = m.w;
                float f5 = have_r ? fr : 0.f;
                if ((s9 == 0 || s9 == 8) && !rv) {
                    f0 = 0.f; f1 = 0.f; f2 = 0.f; f3 = 0.f; f4v = 0.f; f5 = 0.f;
                }
                float f[6] = { f0, f1, f2, f3, f4v, f5 };

                const int jlo = (s9 >= 2) ? s9 - 2 : 0;
                const int jhi = (s9 <= 6) ? s9 : 6;
                #pragma unroll
                for (int j = jlo; j <= jhi; ++j) {
                    const int dh = s9 - j;
                    const float w0t = wgt[dt * 9 + dh * 3 + 0];
                    const float w1t = wgt[dt * 9 + dh * 3 + 1];
                    const float w2t = wgt[dt * 9 + dh * 3 + 2];
                    #pragma unroll
                    for (int k = 0; k < 4; ++k)
                        acc[j][k] += w0t * f[k] + w1t * f[k + 1] + w2t * f[k + 2];
                }
            }
        }
    }

    if (act) {
        float* pp = pbuf + (size_t)sg * THW
                         + (size_t)t * HW + r0 * W_DIM + w0;
        #pragma unroll
        for (int j = 0; j < 7; ++j) {
            float4 v; v.x = acc[j][0]; v.y = acc[j][1]; v.z = acc[j][2]; v.w = acc[j][3];
            *(float4*)(pp + j * W_DIM) = v;
        }
    }
}

// ---------------------------------------------------------------------------
// Reduce S partials per side + bias + tanh -> gbuf (gl at 0, gr at THW).
// ---------------------------------------------------------------------------
template<int S>
__global__ __launch_bounds__(256) void reduce_tanh_kernel(
    const float* __restrict__ pbuf,
    float* __restrict__ gbuf,
    const float* __restrict__ b_l,
    const float* __restrict__ b_r)
{
    const int i = blockIdx.x * 256 + threadIdx.x;   // over THW/4
    const float4* p4 = (const float4*)pbuf;
    float4* g4 = (float4*)gbuf;

    float4 a = {0.f,0.f,0.f,0.f}, b = {0.f,0.f,0.f,0.f};
    #pragma unroll
    for (int g = 0; g < S; ++g) {
        float4 va = p4[(size_t)g       * (THW/4) + i];
        float4 vb = p4[(size_t)(S + g) * (THW/4) + i];
        a.x += va.x; a.y += va.y; a.z += va.z; a.w += va.w;
        b.x += vb.x; b.y += vb.y; b.z += vb.z; b.w += vb.w;
    }
    const float bl = b_l[0], br = b_r[0];
    float4 gl, gr;
    gl.x = tanhf(a.x + bl); gl.y = tanhf(a.y + bl);
    gl.z = tanhf(a.z + bl); gl.w = tanhf(a.w + bl);
    gr.x = tanhf(b.x + br); gr.y = tanhf(b.y + br);
    gr.z = tanhf(b.z + br); gr.w = tanhf(b.w + br);
    g4[i]           = gl;
    g4[(THW/4) + i] = gr;
}

// ---------------------------------------------------------------------------
// Combine: thread owns (c,h,w4), iterates 16 t's carrying x/g in registers.
// Non-temporal stores (out never re-read); NT loads for the c>=128 copy
// stream (gate never touches c>=128 -> keep caches for the hot half of x).
// ---------------------------------------------------------------------------
__global__ __launch_bounds__(256) void combine_kernel(
    const float* __restrict__ x,
    const float* __restrict__ g,
    float* __restrict__ out)
{
    const int tid = blockIdx.x * 256 + threadIdx.x;   // (c*784 + h*14 + w4)
    const int t0  = blockIdx.y * 16;
    const int c   = tid / HW4;
    const int gb  = tid - c * HW4;

    const float4* x4 = (const float4*)x;
    float4*       o4 = (float4*)out;
    const nt_float4* xn4 = (const nt_float4*)x;
    nt_float4*       on4 = (nt_float4*)out;
    const size_t  ts = C_DIM * HW4;
    const size_t  base = tid;

    if (c >= 128) {
        #pragma unroll 4
        for (int i = 0; i < 16; ++i) {
            const size_t idx = (size_t)(t0 + i) * ts + base;
            nt_float4 v = __builtin_nontemporal_load(&xn4[idx]);
            __builtin_nontemporal_store(v, &on4[idx]);
        }
    } else if (c < 64) {
        const float4* gl4 = (const float4*)g;
        float4 xv = x4[(size_t)t0 * ts + base];
        float4 g0 = gl4[t0 * HW4 + gb];
        #pragma unroll 4
        for (int i = 0; i < 16; ++i) {
            const int t  = t0 + i;
            const int tp = (t + 1) & 63;
            float4 xn = x4[(size_t)tp * ts + base];
            float4 g1 = gl4[tp * HW4 + gb];
            nt_float4 r;
            r.x = xv.x - g0.x * xv.x + g1.x * xn.x;
            r.y = xv.y - g0.y * xv.y + g1.y * xn.y;
            r.z = xv.z - g0.z * xv.z + g1.z * xn.z;
            r.w = xv.w - g0.w * xv.w + g1.w * xn.w;
            __builtin_nontemporal_store(r, &on4[(size_t)t * ts + base]);
            xv = xn; g0 = g1;
        }
    } else {
        const float4* gr4 = (const float4*)(g + THW);
        const int tmi = (t0 + 63) & 63;
        float4 xm = x4[(size_t)tmi * ts + base];
        float4 gm = gr4[tmi * HW4 + gb];
        #pragma unroll 4
        for (int i = 0; i < 16; ++i) {
            const int t = t0 + i;
            float4 xv = x4[(size_t)t * ts + base];
            float4 g0 = gr4[t * HW4 + gb];
            nt_float4 r;
            r.x = xv.x - g0.x * xv.x + gm.x * xm.x;
            r.y = xv.y - g0.y * xv.y + gm.y * xm.y;
            r.z = xv.z - g0.z * xv.z + gm.z * xm.z;
            r.w = xv.w - g0.w * xv.w + gm.w * xm.w;
            __builtin_nontemporal_store(r, &on4[(size_t)t * ts + base]);
            xm = xv; gm = g0;
        }
    }
}

template<int S>
static void launch_all(const float* x, const float* w_l, const float* b_l,
                       const float* w_r, const float* b_r,
                       float* out, float* ws, hipStream_t stream)
{
    float* pbuf = ws;                          // 2*S partial planes
    float* gbuf = ws + (size_t)(2 * S) * THW;  // 2 gate planes
    gate_kernel<S><<<2 * S * 32, 256, 0, stream>>>(x, w_l, w_r, pbuf);
    reduce_tanh_kernel<S><<<THW / 4 / 256, 256, 0, stream>>>(pbuf, gbuf, b_l, b_r);
    combine_kernel<<<dim3(HW4 * C_DIM / 256, 4), 256, 0, stream>>>(x, gbuf, out);
}

extern "C" void kernel_launch(void* const* d_in, const int* in_sizes, int n_in,
                              void* d_out, int out_size, void* d_ws, size_t ws_size,
                              hipStream_t stream) {
    const float* x   = (const float*)d_in[0];
    const float* w_l = (const float*)d_in[1];
    const float* b_l = (const float*)d_in[2];
    const float* w_r = (const float*)d_in[3];
    const float* b_r = (const float*)d_in[4];
    float* out = (float*)d_out;
    float* ws  = (float*)d_ws;

    const size_t plane_bytes = (size_t)THW * 4;
    if (ws_size >= 34 * plane_bytes)
        launch_all<16>(x, w_l, b_l, w_r, b_r, out, ws, stream);
    else if (ws_size >= 18 * plane_bytes)
        launch_all<8>(x, w_l, b_l, w_r, b_r, out, ws, stream);
    else
        launch_all<4>(x, w_l, b_l, w_r, b_r, out, ws, stream);
}

// Round 10
// 110.249 us; speedup vs baseline: 3.4945x; 1.0285x over previous
//
#include <hip/hip_runtime.h>
#include <math.h>

#define T_DIM 64
#define C_DIM 256
#define H_DIM 56
#define W_DIM 56
#define HW    (H_DIM * W_DIM)        // 3136
#define HW4   (HW / 4)               // 784
#define CHW   (C_DIM * HW)
#define THW   (T_DIM * HW)           // 200704

typedef float nt_float4 __attribute__((ext_vector_type(4)));

// force a (wave-uniform) float into an SGPR
__device__ __forceinline__ float rfl(float v) {
    return __int_as_float(__builtin_amdgcn_readfirstlane(__float_as_int(v)));
}

// ---------------------------------------------------------------------------
// Kernel 1: gate blocks (XCD-swizzled) + copy blocks (c>=128 passthrough).
// Gate: blocks [0, 2*S*32). XCD swizzle: xcd = p&7 owns sgs [xcd*2S/8, ...),
// so all 32 tq-blocks of one sg share one XCD's L2 -> t-halo planes fetched
// once. wave: hh = waveid&1, t = tq*2 + (waveid>>1). lane: wg=lane&15
// (active<14), rg=lane>>4; rows r0..r0+6, cols w0..w0+3. Per (ci,dt,row):
// ONE float4 load; halo cols via shfl. Weights -> SGPRs via readfirstlane.
// Copy: blocks [2*S*32, +1568): NT float4 copy of the c>=128 half, 16 t's
// per thread. Overlaps its HBM stream with the latency-bound gate blocks.
// ---------------------------------------------------------------------------
template<int S>
__global__ __launch_bounds__(256) void gate_copy_kernel(
    const float* __restrict__ x,
    const float* __restrict__ w_l,
    const float* __restrict__ w_r,
    float* __restrict__ pbuf,
    float* __restrict__ out)
{
    constexpr int CPG   = 64 / S;
    constexpr int NGATE = 2 * S * 32;

    const int p = blockIdx.x;

    if (p >= NGATE) {
        // ---------------- copy path: c >= 128 ----------------
        const int qq     = p - NGATE;
        const int tchunk = qq / 392;
        const int bx2    = qq - tchunk * 392;
        const int tid    = 128 * HW4 + bx2 * 256 + (int)threadIdx.x;
        const int t0     = tchunk * 16;

        const nt_float4* xn4 = (const nt_float4*)x;
        nt_float4*       on4 = (nt_float4*)out;
        const size_t ts = C_DIM * HW4;

        #pragma unroll 4
        for (int i = 0; i < 16; ++i) {
            const size_t idx = (size_t)(t0 + i) * ts + tid;
            nt_float4 v = __builtin_nontemporal_load(&xn4[idx]);
            __builtin_nontemporal_store(v, &on4[idx]);
        }
        return;
    }

    // ---------------- gate path ----------------
    const int xcd = p & 7;
    const int s   = p >> 3;
    const int sg  = xcd * (2 * S / 8) + (s >> 5);   // block-uniform
    const int tq  = s & 31;
    const int side = sg / S;
    const int g    = sg & (S - 1);

    const int waveid = __builtin_amdgcn_readfirstlane((int)(threadIdx.x >> 6));
    const int hh = waveid & 1;
    const int t  = tq * 2 + (waveid >> 1);

    const int lane = threadIdx.x & 63;
    const int wg   = lane & 15;
    const int rg   = lane >> 4;
    const bool act = (wg < 14);
    const int w0   = act ? wg * 4 : 52;
    const int r0   = hh * 28 + rg * 7;
    const bool have_l = (wg > 0);
    const bool have_r = (wg < 13);

    const float* wtab = (side ? w_r : w_l) + g * CPG * 27;   // uniform
    const int c0 = side * 64 + g * CPG;

    const int tm = (t + 63) & 63, tp = (t + 1) & 63;
    const float* tbase[3] = { x + (size_t)tm * CHW,
                              x + (size_t)t  * CHW,
                              x + (size_t)tp * CHW };

    float acc[7][4];
    #pragma unroll
    for (int j = 0; j < 7; ++j)
        #pragma unroll
        for (int k = 0; k < 4; ++k) acc[j][k] = 0.f;

    #pragma unroll 1
    for (int ci = 0; ci < CPG; ++ci) {
        float wgt[27];
        #pragma unroll
        for (int k = 0; k < 27; ++k) wgt[k] = rfl(wtab[ci * 27 + k]);  // SGPRs

        #pragma unroll
        for (int dt = 0; dt < 3; ++dt) {
            const float* plane = tbase[dt] + (size_t)(c0 + ci) * HW;

            #pragma unroll
            for (int s9 = 0; s9 < 9; ++s9) {
                const int sr = r0 - 1 + s9;
                bool rv = true;
                int  srow = sr;
                if (s9 == 0)      { rv = (sr >= 0);     srow = rv ? sr : 0; }
                else if (s9 == 8) { rv = (sr < H_DIM);  srow = rv ? sr : (H_DIM - 1); }

                const float* row = plane + srow * W_DIM;
                float4 m  = *(const float4*)(row + w0);
                float  fl = __shfl_up(m.w, 1);    // lane-1's row[w0+3] == row[w0-1]
                float  fr = __shfl_down(m.x, 1);  // lane+1's row[w0]   == row[w0+4]

                float f0 = have_l ? fl : 0.f;
                float f1 = m.x, f2 = m.y, f3 = m.z, f4v = m.w;
                float f5 = have_r ? fr : 0.f;
                if ((s9 == 0 || s9 == 8) && !rv) {
                    f0 = 0.f; f1 = 0.f; f2 = 0.f; f3 = 0.f; f4v = 0.f; f5 = 0.f;
                }
                float f[6] = { f0, f1, f2, f3, f4v, f5 };

                const int jlo = (s9 >= 2) ? s9 - 2 : 0;
                const int jhi = (s9 <= 6) ? s9 : 6;
                #pragma unroll
                for (int j = jlo; j <= jhi; ++j) {
                    const int dh = s9 - j;
                    const float w0t = wgt[dt * 9 + dh * 3 + 0];
                    const float w1t = wgt[dt * 9 + dh * 3 + 1];
                    const float w2t = wgt[dt * 9 + dh * 3 + 2];
                    #pragma unroll
                    for (int k = 0; k < 4; ++k)
                        acc[j][k] += w0t * f[k] + w1t * f[k + 1] + w2t * f[k + 2];
                }
            }
        }
    }

    if (act) {
        float* pp = pbuf + (size_t)sg * THW
                         + (size_t)t * HW + r0 * W_DIM + w0;
        #pragma unroll
        for (int j = 0; j < 7; ++j) {
            float4 v; v.x = acc[j][0]; v.y = acc[j][1]; v.z = acc[j][2]; v.w = acc[j][3];
            *(float4*)(pp + j * W_DIM) = v;
        }
    }
}

// ---------------------------------------------------------------------------
// Reduce S partials per side + bias + tanh -> gbuf (gl at 0, gr at THW).
// ---------------------------------------------------------------------------
template<int S>
__global__ __launch_bounds__(256) void reduce_tanh_kernel(
    const float* __restrict__ pbuf,
    float* __restrict__ gbuf,
    const float* __restrict__ b_l,
    const float* __restrict__ b_r)
{
    const int i = blockIdx.x * 256 + threadIdx.x;   // over THW/4
    const float4* p4 = (const float4*)pbuf;
    float4* g4 = (float4*)gbuf;

    float4 a = {0.f,0.f,0.f,0.f}, b = {0.f,0.f,0.f,0.f};
    #pragma unroll
    for (int g = 0; g < S; ++g) {
        float4 va = p4[(size_t)g       * (THW/4) + i];
        float4 vb = p4[(size_t)(S + g) * (THW/4) + i];
        a.x += va.x; a.y += va.y; a.z += va.z; a.w += va.w;
        b.x += vb.x; b.y += vb.y; b.z += vb.z; b.w += vb.w;
    }
    const float bl = b_l[0], br = b_r[0];
    float4 gl, gr;
    gl.x = tanhf(a.x + bl); gl.y = tanhf(a.y + bl);
    gl.z = tanhf(a.z + bl); gl.w = tanhf(a.w + bl);
    gr.x = tanhf(b.x + br); gr.y = tanhf(b.y + br);
    gr.z = tanhf(b.z + br); gr.w = tanhf(b.w + br);
    g4[i]           = gl;
    g4[(THW/4) + i] = gr;
}

// ---------------------------------------------------------------------------
// Combine (c < 128 only): thread owns (c,h,w4), iterates 16 t's carrying
// x/g in registers. NT stores (out never re-read).
// ---------------------------------------------------------------------------
__global__ __launch_bounds__(256) void combine_kernel(
    const float* __restrict__ x,
    const float* __restrict__ g,
    float* __restrict__ out)
{
    const int tid = blockIdx.x * 256 + threadIdx.x;   // c in [0,128)
    const int t0  = blockIdx.y * 16;
    const int c   = tid / HW4;
    const int gb  = tid - c * HW4;

    const float4* x4 = (const float4*)x;
    nt_float4*    on4 = (nt_float4*)out;
    const size_t  ts = C_DIM * HW4;
    const size_t  base = tid;

    if (c < 64) {
        const float4* gl4 = (const float4*)g;
        float4 xv = x4[(size_t)t0 * ts + base];
        float4 g0 = gl4[t0 * HW4 + gb];
        #pragma unroll 4
        for (int i = 0; i < 16; ++i) {
            const int t  = t0 + i;
            const int tp = (t + 1) & 63;
            float4 xn = x4[(size_t)tp * ts + base];
            float4 g1 = gl4[tp * HW4 + gb];
            nt_float4 r;
            r.x = xv.x - g0.x * xv.x + g1.x * xn.x;
            r.y = xv.y - g0.y * xv.y + g1.y * xn.y;
            r.z = xv.z - g0.z * xv.z + g1.z * xn.z;
            r.w = xv.w - g0.w * xv.w + g1.w * xn.w;
            __builtin_nontemporal_store(r, &on4[(size_t)t * ts + base]);
            xv = xn; g0 = g1;
        }
    } else {
        const float4* gr4 = (const float4*)(g + THW);
        const int tmi = (t0 + 63) & 63;
        float4 xm = x4[(size_t)tmi * ts + base];
        float4 gm = gr4[tmi * HW4 + gb];
        #pragma unroll 4
        for (int i = 0; i < 16; ++i) {
            const int t = t0 + i;
            float4 xv = x4[(size_t)t * ts + base];
            float4 g0 = gr4[t * HW4 + gb];
            nt_float4 r;
            r.x = xv.x - g0.x * xv.x + gm.x * xm.x;
            r.y = xv.y - g0.y * xv.y + gm.y * xm.y;
            r.z = xv.z - g0.z * xv.z + gm.z * xm.z;
            r.w = xv.w - g0.w * xv.w + gm.w * xm.w;
            __builtin_nontemporal_store(r, &on4[(size_t)t * ts + base]);
            xm = xv; gm = g0;
        }
    }
}

template<int S>
static void launch_all(const float* x, const float* w_l, const float* b_l,
                       const float* w_r, const float* b_r,
                       float* out, float* ws, hipStream_t stream)
{
    float* pbuf = ws;                          // 2*S partial planes
    float* gbuf = ws + (size_t)(2 * S) * THW;  // 2 gate planes

    const int ngate = 2 * S * 32;
    const int ncopy = 392 * 4;                 // c>=128 half, 16 t per thread
    gate_copy_kernel<S><<<ngate + ncopy, 256, 0, stream>>>(x, w_l, w_r, pbuf, out);
    reduce_tanh_kernel<S><<<THW / 4 / 256, 256, 0, stream>>>(pbuf, gbuf, b_l, b_r);
    combine_kernel<<<dim3(392, 4), 256, 0, stream>>>(x, gbuf, out);
}

extern "C" void kernel_launch(void* const* d_in, const int* in_sizes, int n_in,
                              void* d_out, int out_size, void* d_ws, size_t ws_size,
                              hipStream_t stream) {
    const float* x   = (const float*)d_in[0];
    const float* w_l = (const float*)d_in[1];
    const float* b_l = (const float*)d_in[2];
    const float* w_r = (const float*)d_in[3];
    const float* b_r = (const float*)d_in[4];
    float* out = (float*)d_out;
    float* ws  = (float*)d_ws;

    const size_t plane_bytes = (size_t)THW * 4;
    if (ws_size >= 34 * plane_bytes)
        launch_all<16>(x, w_l, b_l, w_r, b_r, out, ws, stream);
    else if (ws_size >= 18 * plane_bytes)
        launch_all<8>(x, w_l, b_l, w_r, b_r, out, ws, stream);
    else
        launch_all<4>(x, w_l, b_l, w_r, b_r, out, ws, stream);
}